// Round 2
// baseline (740.571 us; speedup 1.0000x reference)
//
#include <hip/hip_runtime.h>
#include <hip/hip_bf16.h>
#include <math.h>

// LMU-FFT: x(32,4096,256), W_u(1,256), W_h(512,512), H(256,4096) -> h(32,4096,512), h_n(32,512)
//
// Round-2 structure (iFFT-then-GEMM, fragment-native layouts):
//   u = relu(x@W_u)            relu_u_kernel (also emits xh = fp16(x))
//   Uf, Hf = FFT(u), FFT(H)    fwd_all_kernel (radix-4, digit-reversed order)
//   m = iFFT(Uf .* Hf-pairs)   conv_m_kernel: 4 iFFTs/block, results packed fp16 into
//                              m2[q/8][b*T+t][q%8]  (16B-coalesced stores, k-blocked)
//   h = relu([m|x] @ W_h^T)    h_gemm_kernel: NO LDS, NO barriers - every MFMA fragment
//                              is one 16B global load (m2 / xh / whf all fp16 k-blocked)
// The k-blocked fp16 layout matches the mfma_f32_16x16x32_f16 A/B fragment
// (lane&15 = row, lane>>4 = k-octet), so operands go global->VGPR directly.
// Numerics: identical rounding points to the previously verified kernel.

#define BATCH 32
#define T     4096
#define IND   256
#define HID   512
#define MEM   256
#define FFT_N 8192
#define FFT_LOG 13
#define BT    131072   // BATCH*T

typedef __attribute__((ext_vector_type(8))) short short8;
typedef __attribute__((ext_vector_type(8))) _Float16 half8;
typedef __attribute__((ext_vector_type(4))) float f32x4;

__device__ inline short f2bf(float f) {
    unsigned u = __float_as_uint(f);
    unsigned r = (u + 0x7FFFu + ((u >> 16) & 1u)) >> 16;
    return (short)r;
}
__device__ inline unsigned pk2h(float a, float b) {
    union { _Float16 h[2]; unsigned u; } v;
    v.h[0] = (_Float16)a; v.h[1] = (_Float16)b;
    return v.u;
}

// ============================ kernel 1 ============================
// u[b,t] = relu(dot(x[b,t,:], W_u));  xh = fp16(x)
__global__ __launch_bounds__(256) void relu_u_kernel(const float* __restrict__ x,
                                                     const float* __restrict__ Wu,
                                                     float* __restrict__ u,
                                                     _Float16* __restrict__ xh) {
    int wave = threadIdx.x >> 6, lane = threadIdx.x & 63;
    int r = blockIdx.x * 4 + wave;
    const float4 xv = *(const float4*)(x + (size_t)r * IND + lane * 4);
    const float4 wv = *(const float4*)(Wu + lane * 4);
    union { _Float16 h[4]; uint2 u2; } hv;
    hv.h[0] = (_Float16)xv.x; hv.h[1] = (_Float16)xv.y;
    hv.h[2] = (_Float16)xv.z; hv.h[3] = (_Float16)xv.w;
    *(uint2*)(xh + (size_t)r * IND + lane * 4) = hv.u2;
    float acc = xv.x * wv.x + xv.y * wv.y + xv.z * wv.z + xv.w * wv.w;
    for (int off = 32; off; off >>= 1) acc += __shfl_down(acc, off);
    if (lane == 0) u[r] = fmaxf(acc, 0.f);
}

// ============================ kernel 1b ============================
// whf = fp16(W_h)   (512x512, row-major [o][k])
__global__ __launch_bounds__(256) void wh_half_kernel(const float* __restrict__ Wh,
                                                      _Float16* __restrict__ whf) {
    int i = blockIdx.x * 256 + threadIdx.x;           // 0..65535, each does 4 elems
    float4 v = *(const float4*)(Wh + (size_t)i * 4);
    union { _Float16 h[4]; uint2 u2; } hv;
    hv.h[0] = (_Float16)v.x; hv.h[1] = (_Float16)v.y;
    hv.h[2] = (_Float16)v.z; hv.h[3] = (_Float16)v.w;
    *(uint2*)(whf + (size_t)i * 4) = hv.u2;
}

// ======================= radix-4 FFTs ==========================
// forward DIF: natural -> base-4-digit-reversed. Stages: R2(half=4096), R4 q=1024..1.
__device__ void fft_fwd_r4(float* re, float* im) {
    __syncthreads();
    {   // radix-2 stage, half = 4096
        const float fm = -(float)M_PI / 4096.f;
#pragma unroll
        for (int s = 0; s < 8; ++s) {
            int k = threadIdx.x + s * 512;
            float sn, cs; __sincosf(fm * (float)k, &sn, &cs);
            float ar = re[k], ai = im[k], br = re[k + 4096], bi = im[k + 4096];
            re[k] = ar + br; im[k] = ai + bi;
            float dr = ar - br, di = ai - bi;
            re[k + 4096] = cs * dr - sn * di;
            im[k + 4096] = cs * di + sn * dr;
        }
        __syncthreads();
    }
    for (int st = 10; st >= 0; st -= 2) {
        int q = 1 << st;
        float fm = -(float)M_PI / (float)(2 * q);
#pragma unroll
        for (int s = 0; s < 4; ++s) {
            int k = threadIdx.x + s * 512;
            int j = k & (q - 1);
            int i0 = ((k >> st) << (st + 2)) + j;
            float ar = re[i0],         ai = im[i0];
            float br = re[i0 + q],     bi = im[i0 + q];
            float cr = re[i0 + 2 * q], ci = im[i0 + 2 * q];
            float dr = re[i0 + 3 * q], di = im[i0 + 3 * q];
            float t0r = ar + cr, t0i = ai + ci;
            float t1r = ar - cr, t1i = ai - ci;
            float t2r = br + dr, t2i = bi + di;
            float t3r = bi - di, t3i = dr - br;      // -i*(b-d)
            float sn, cs; __sincosf(fm * (float)j, &sn, &cs);   // w = cs + i*sn
            float w2r = cs * cs - sn * sn, w2i = 2.f * cs * sn; // w^2
            float w3r = w2r * cs - w2i * sn, w3i = w2r * sn + w2i * cs; // w^3
            re[i0] = t0r + t2r;               im[i0] = t0i + t2i;
            float er = t0r - t2r, ei = t0i - t2i;
            re[i0 + q] = er * w2r - ei * w2i; im[i0 + q] = er * w2i + ei * w2r;
            float fr = t1r + t3r, fi = t1i + t3i;
            re[i0 + 2 * q] = fr * cs - fi * sn; im[i0 + 2 * q] = fr * sn + fi * cs;
            float gr = t1r - t3r, gi = t1i - t3i;
            re[i0 + 3 * q] = gr * w3r - gi * w3i; im[i0 + 3 * q] = gr * w3i + gi * w3r;
        }
        __syncthreads();
    }
}
// inverse (unscaled): digit-reversed -> natural. Exact transpose of fwd.
// Runtime stage loop (keeps code compact: conv_m inlines this 4x).
__device__ void fft_inv_r4(float* re, float* im) {
    __syncthreads();
    for (int st = 0; st <= 10; st += 2) {
        int q = 1 << st;
        float fm = (float)M_PI / (float)(2 * q);       // conj twiddles
#pragma unroll
        for (int s = 0; s < 4; ++s) {
            int k = threadIdx.x + s * 512;
            int j = k & (q - 1);
            int i0 = ((k >> st) << (st + 2)) + j;
            float Ar = re[i0],         Ai = im[i0];
            float Br = re[i0 + q],     Bi = im[i0 + q];
            float Cr = re[i0 + 2 * q], Ci = im[i0 + 2 * q];
            float Dr = re[i0 + 3 * q], Di = im[i0 + 3 * q];
            float sn, cs; __sincosf(fm * (float)j, &sn, &cs);   // wbar = cs + i*sn
            float w2r = cs * cs - sn * sn, w2i = 2.f * cs * sn;
            float w3r = w2r * cs - w2i * sn, w3i = w2r * sn + w2i * cs;
            float bpr = Br * w2r - Bi * w2i, bpi = Br * w2i + Bi * w2r;
            float cpr = Cr * cs - Ci * sn,   cpi = Cr * sn + Ci * cs;
            float dpr = Dr * w3r - Di * w3i, dpi = Dr * w3i + Di * w3r;
            float t0r = Ar + bpr, t0i = Ai + bpi;
            float t2r = Ar - bpr, t2i = Ai - bpi;
            float t1r = cpr + dpr, t1i = cpi + dpi;
            float t3r = cpr - dpr, t3i = cpi - dpi;
            re[i0]         = t0r + t1r; im[i0]         = t0i + t1i;
            re[i0 + 2 * q] = t0r - t1r; im[i0 + 2 * q] = t0i - t1i;
            re[i0 + q]     = t2r - t3i; im[i0 + q]     = t2i + t3r;  // t2' + i*t3'
            re[i0 + 3 * q] = t2r + t3i; im[i0 + 3 * q] = t2i - t3r;  // t2' - i*t3'
        }
        __syncthreads();
    }
    {   // radix-2 stage, half = 4096, conj twiddle
        const float fm = (float)M_PI / 4096.f;
#pragma unroll
        for (int s = 0; s < 8; ++s) {
            int k = threadIdx.x + s * 512;
            float sn, cs; __sincosf(fm * (float)k, &sn, &cs);
            float br = re[k + 4096], bi = im[k + 4096];
            float tr = cs * br - sn * bi, ti = cs * bi + sn * br;
            float ar = re[k], ai = im[k];
            re[k] = ar + tr;        im[k] = ai + ti;
            re[k + 4096] = ar - tr; im[k + 4096] = ai - ti;
        }
        __syncthreads();
    }
}

// ============================ kernel 2 ============================
// forward FFTs of u rows (blocks 0..31) and H rows (blocks 32..287)
__global__ __launch_bounds__(512) void fwd_all_kernel(const float* __restrict__ u,
                                                      const float* __restrict__ H,
                                                      float2* __restrict__ Uf,
                                                      float2* __restrict__ Hf) {
    __shared__ float re[FFT_N];
    __shared__ float im[FFT_N];
    int r = blockIdx.x;
    const float* src = (r < BATCH) ? (u + (size_t)r * T) : (H + (size_t)(r - BATCH) * T);
    float2* dst = (r < BATCH) ? (Uf + (size_t)r * FFT_N) : (Hf + (size_t)(r - BATCH) * FFT_N);
    for (int i = threadIdx.x; i < FFT_N; i += 512) {
        re[i] = (i < T) ? src[i] : 0.f;
        im[i] = 0.f;
    }
    fft_fwd_r4(re, im);
    for (int i = threadIdx.x; i < FFT_N; i += 512) dst[i] = make_float2(re[i], im[i]);
}

// ============================ kernel 3 ============================
// per (qblock, b): 4 iFFTs (8 q-channels), pack fp16, write m2[qb][b*T+t][0..7]
// Thread-local re/im slots {tid + 512k} are read and rewritten only by the owner
// thread between the fft's internal barriers -> no extra barriers needed.
__global__ __launch_bounds__(512) void conv_m_kernel(const float2* __restrict__ Uf,
                                                     const float2* __restrict__ Hf,
                                                     _Float16* __restrict__ m2) {
    int qb = blockIdx.x;   // 0..31
    int b  = blockIdx.y;   // 0..31
    __shared__ float re[FFT_N];
    __shared__ float im[FFT_N];
    const float2* Ub = Uf + (size_t)b * FFT_N;
    const float inv = 1.0f / (float)FFT_N;
    unsigned p0[8], p1[8], p2[8], p3[8];

#define DO_FF(FF, PK)                                                          \
    {                                                                          \
        const float2* Ha = Hf + (size_t)(qb * 8 + 2 * (FF)) * FFT_N;           \
        const float2* Hb = Ha + FFT_N;                                         \
        for (int f = threadIdx.x; f < FFT_N; f += 512) {                       \
            float2 uv = Ub[f], h0 = Ha[f], h1 = Hb[f];                         \
            float gr = h0.x - h1.y, gi = h0.y + h1.x;  /* h0 + i*h1 */         \
            re[f] = uv.x * gr - uv.y * gi;                                     \
            im[f] = uv.x * gi + uv.y * gr;                                     \
        }                                                                      \
        fft_inv_r4(re, im);                                                    \
        _Pragma("unroll")                                                      \
        for (int it = 0; it < 8; ++it) {                                       \
            int tt = threadIdx.x + it * 512;                                   \
            PK[it] = pk2h(re[tt] * inv, im[tt] * inv);                         \
        }                                                                      \
    }

    DO_FF(0, p0)
    DO_FF(1, p1)
    DO_FF(2, p2)
    DO_FF(3, p3)
#undef DO_FF

    _Float16* dst = m2 + ((size_t)qb * BT + (size_t)b * T) * 8;
#pragma unroll
    for (int it = 0; it < 8; ++it) {
        int tt = threadIdx.x + it * 512;
        uint4 w;
        w.x = p0[it]; w.y = p1[it]; w.z = p2[it]; w.w = p3[it];
        *(uint4*)(dst + (size_t)tt * 8) = w;   // 16B, fully coalesced over t
    }
}

// ============================ kernel 4 ============================
// h = relu([m | x] @ W_h^T), fp16 MFMA, K=512. 128x128 tile, 4 waves, NO LDS.
// A-fragment (8 consecutive k at row m=lane&15, octet kg=lane>>4) is one 16B load:
//   k<256:  m2[(kc>>3)+kg][row][0..7]
//   k>=256: xh[row][(kc-256)+kg*8 ..]
// B-fragment: whf[col][kc+kg*8 ..]   (0.5 MB, L2-resident)
__global__ __launch_bounds__(256) void h_gemm_kernel(const _Float16* __restrict__ xh,
                                                     const _Float16* __restrict__ whf,
                                                     const _Float16* __restrict__ m2,
                                                     float* __restrict__ out) {
    int bn = blockIdx.x;     // 0..3
    int bm = blockIdx.y;     // 0..1023
    int t = threadIdx.x;
    int wv = t >> 6, lane = t & 63;
    int wm = (wv & 1) * 64, wn = (wv >> 1) * 64;
    int ln = lane & 15, kg = lane >> 4;
    int row0 = bm * 128 + wm + ln;
    int col0 = bn * 128 + wn + ln;

    f32x4 acc[4][4] = {};
#pragma unroll
    for (int kc = 0; kc < HID; kc += 32) {
        half8 af[4], bf[4];
        if (kc < MEM) {
#pragma unroll
            for (int i = 0; i < 4; ++i)
                af[i] = *(const half8*)(m2 + ((size_t)(kc / 8 + kg) * BT + row0 + i * 16) * 8);
        } else {
#pragma unroll
            for (int i = 0; i < 4; ++i)
                af[i] = *(const half8*)(xh + (size_t)(row0 + i * 16) * IND + (kc - MEM) + kg * 8);
        }
#pragma unroll
        for (int j = 0; j < 4; ++j)
            bf[j] = *(const half8*)(whf + (size_t)(col0 + j * 16) * HID + kc + kg * 8);
#pragma unroll
        for (int i = 0; i < 4; ++i)
#pragma unroll
            for (int j = 0; j < 4; ++j)
                acc[i][j] = __builtin_amdgcn_mfma_f32_16x16x32_f16(af[i], bf[j], acc[i][j], 0, 0, 0);
    }
#pragma unroll
    for (int i = 0; i < 4; ++i) {
#pragma unroll
        for (int j = 0; j < 4; ++j) {
#pragma unroll
            for (int r = 0; r < 4; ++r) {
                int row = bm * 128 + wm + i * 16 + kg * 4 + r;
                int col = bn * 128 + wn + j * 16 + ln;
                float v = fmaxf(acc[i][j][r], 0.f);
                out[(size_t)row * HID + col] = v;
                if ((row & (T - 1)) == (T - 1))
                    out[(size_t)BATCH * T * HID + (size_t)(row >> 12) * HID + col] = v;
            }
        }
    }
}

// ================== OLD PATH (verbatim fallback, small ws) ==================
__device__ void fft_dif_fwd(float* re, float* im) {
    __syncthreads();
    for (int st = FFT_LOG; st >= 1; --st) {
        int half = 1 << (st - 1);
        float fm = -(float)M_PI / (float)half;
        for (int k = threadIdx.x; k < FFT_N / 2; k += 512) {
            int j  = k & (half - 1);
            int i1 = ((k >> (st - 1)) << st) + j;
            int i2 = i1 + half;
            float sn, cs;
            __sincosf(fm * (float)j, &sn, &cs);
            float ar = re[i1], ai = im[i1];
            float br = re[i2], bi = im[i2];
            re[i1] = ar + br; im[i1] = ai + bi;
            float dr = ar - br, di = ai - bi;
            re[i2] = cs * dr - sn * di;
            im[i2] = cs * di + sn * dr;
        }
        __syncthreads();
    }
}
__device__ void fft_dit_inv(float* re, float* im) {
    __syncthreads();
    for (int st = 1; st <= FFT_LOG; ++st) {
        int half = 1 << (st - 1);
        float fm = (float)M_PI / (float)half;
        for (int k = threadIdx.x; k < FFT_N / 2; k += 512) {
            int j  = k & (half - 1);
            int i1 = ((k >> (st - 1)) << st) + j;
            int i2 = i1 + half;
            float sn, cs;
            __sincosf(fm * (float)j, &sn, &cs);
            float br = re[i2], bi = im[i2];
            float tr = cs * br - sn * bi;
            float ti = cs * bi + sn * br;
            float ar = re[i1], ai = im[i1];
            re[i1] = ar + tr; im[i1] = ai + ti;
            re[i2] = ar - tr; im[i2] = ai - ti;
        }
        __syncthreads();
    }
}
__global__ __launch_bounds__(512) void fft_u_kernel(const float* __restrict__ u,
                                                    float2* __restrict__ Uf) {
    int b = blockIdx.x;
    __shared__ float re[FFT_N];
    __shared__ float im[FFT_N];
    for (int i = threadIdx.x; i < FFT_N; i += 512) {
        re[i] = i < T ? u[(size_t)b * T + i] : 0.f;
        im[i] = 0.f;
    }
    fft_dif_fwd(re, im);
    for (int i = threadIdx.x; i < FFT_N; i += 512)
        Uf[(size_t)b * FFT_N + i] = make_float2(re[i], im[i]);
}
__global__ __launch_bounds__(512) void g_fft_kernel(const float* __restrict__ Wh,
                                                    const float* __restrict__ H,
                                                    float2* __restrict__ Gf) {
    int o = blockIdx.x;
    __shared__ float re[FFT_N];
    __shared__ float im[FFT_N];
    const float* wrow = Wh + (size_t)o * HID;
    float acc[8];
#pragma unroll
    for (int d = 0; d < 8; ++d) acc[d] = 0.f;
    for (int q = 0; q < 256; ++q) {
        float w = wrow[q];
        const float* hrow = H + (size_t)q * T;
#pragma unroll
        for (int d = 0; d < 8; ++d)
            acc[d] = fmaf(w, hrow[threadIdx.x + d * 512], acc[d]);
    }
#pragma unroll
    for (int d = 0; d < 8; ++d) {
        re[threadIdx.x + d * 512] = acc[d];
        im[threadIdx.x + d * 512] = 0.f;
    }
    for (int i = T + threadIdx.x; i < FFT_N; i += 512) { re[i] = 0.f; im[i] = 0.f; }
    fft_dif_fwd(re, im);
    for (int i = threadIdx.x; i < FFT_N; i += 512)
        Gf[(size_t)o * FFT_N + i] = make_float2(re[i], im[i]);
}
__global__ __launch_bounds__(256) void xw_gemm_kernel(const float* __restrict__ x,
                                                      const float* __restrict__ Wh,
                                                      float* __restrict__ out) {
    __shared__ __align__(16) short Asl[4][128][8];
    __shared__ __align__(16) short Bsl[4][128][8];
    int bn = blockIdx.x;
    int bm = blockIdx.y;
    int t = threadIdx.x;
    int wv = t >> 6, lane = t & 63;
    int wm = (wv & 1) * 64, wn = (wv >> 1) * 64;
    int ln = lane & 15, kg = lane >> 4;
    f32x4 acc[4][4] = {};
    int mrow = t >> 1, khalf = t & 1;
    for (int kc = 0; kc < IND; kc += 32) {
        {
            const float* xr = x + ((size_t)(bm * 128 + mrow)) * IND + kc + khalf * 16;
            float4 v0 = *(const float4*)(xr + 0);
            float4 v1 = *(const float4*)(xr + 4);
            float4 v2 = *(const float4*)(xr + 8);
            float4 v3 = *(const float4*)(xr + 12);
            short8 s0 = { f2bf(v0.x), f2bf(v0.y), f2bf(v0.z), f2bf(v0.w),
                          f2bf(v1.x), f2bf(v1.y), f2bf(v1.z), f2bf(v1.w) };
            short8 s1 = { f2bf(v2.x), f2bf(v2.y), f2bf(v2.z), f2bf(v2.w),
                          f2bf(v3.x), f2bf(v3.y), f2bf(v3.z), f2bf(v3.w) };
            const float* wr = Wh + ((size_t)(bn * 128 + mrow)) * HID + 256 + kc + khalf * 16;
            float4 w0 = *(const float4*)(wr + 0);
            float4 w1 = *(const float4*)(wr + 4);
            float4 w2 = *(const float4*)(wr + 8);
            float4 w3 = *(const float4*)(wr + 12);
            short8 b0 = { f2bf(w0.x), f2bf(w0.y), f2bf(w0.z), f2bf(w0.w),
                          f2bf(w1.x), f2bf(w1.y), f2bf(w1.z), f2bf(w1.w) };
            short8 b1 = { f2bf(w2.x), f2bf(w2.y), f2bf(w2.z), f2bf(w2.w),
                          f2bf(w3.x), f2bf(w3.y), f2bf(w3.z), f2bf(w3.w) };
            __syncthreads();
            *(short8*)&Asl[khalf * 2 + 0][mrow][0] = s0;
            *(short8*)&Asl[khalf * 2 + 1][mrow][0] = s1;
            *(short8*)&Bsl[khalf * 2 + 0][mrow][0] = b0;
            *(short8*)&Bsl[khalf * 2 + 1][mrow][0] = b1;
            __syncthreads();
        }
        short8 af[4], bf[4];
#pragma unroll
        for (int i = 0; i < 4; ++i) af[i] = *(short8*)&Asl[kg][wm + i * 16 + ln][0];
#pragma unroll
        for (int j = 0; j < 4; ++j) bf[j] = *(short8*)&Bsl[kg][wn + j * 16 + ln][0];
#pragma unroll
        for (int i = 0; i < 4; ++i)
#pragma unroll
            for (int j = 0; j < 4; ++j)
                acc[i][j] = __builtin_amdgcn_mfma_f32_16x16x32_bf16(af[i], bf[j], acc[i][j], 0, 0, 0);
    }
#pragma unroll
    for (int i = 0; i < 4; ++i) {
#pragma unroll
        for (int j = 0; j < 4; ++j) {
#pragma unroll
            for (int r = 0; r < 4; ++r) {
                int row = bm * 128 + wm + i * 16 + (lane >> 4) * 4 + r;
                int col = bn * 128 + wn + j * 16 + (lane & 15);
                out[(size_t)row * HID + col] = acc[i][j][r];
            }
        }
    }
}
__global__ __launch_bounds__(512) void conv_apply_kernel(const float2* __restrict__ Uf,
                                                         const float2* __restrict__ Gf,
                                                         float* __restrict__ out) {
    int p = blockIdx.x;
    int b = blockIdx.y;
    __shared__ float re[FFT_N];
    __shared__ float im[FFT_N];
    const float2* Ub = Uf + (size_t)b * FFT_N;
    const float2* G0 = Gf + (size_t)(2 * p) * FFT_N;
    const float2* G1 = Gf + (size_t)(2 * p + 1) * FFT_N;
    for (int f = threadIdx.x; f < FFT_N; f += 512) {
        float2 uv = Ub[f], g0 = G0[f], g1 = G1[f];
        float gr = g0.x - g1.y, gi = g0.y + g1.x;
        re[f] = uv.x * gr - uv.y * gi;
        im[f] = uv.x * gi + uv.y * gr;
    }
    fft_dit_inv(re, im);
    const float inv = 1.0f / (float)FFT_N;
    for (int t = threadIdx.x; t < T; t += 512) {
        size_t idx = ((size_t)(b * T + t)) * HID + 2 * p;
        float2 xw = *(const float2*)(out + idx);
        float v0 = fmaxf(fmaf(re[t], inv, xw.x), 0.f);
        float v1 = fmaxf(fmaf(im[t], inv, xw.y), 0.f);
        *(float2*)(out + idx) = make_float2(v0, v1);
        if (t == T - 1) {
            size_t hn = (size_t)BATCH * T * HID + (size_t)b * HID + 2 * p;
            *(float2*)(out + hn) = make_float2(v0, v1);
        }
    }
}

// ============================== launch ==============================
extern "C" void kernel_launch(void* const* d_in, const int* in_sizes, int n_in,
                              void* d_out, int out_size, void* d_ws, size_t ws_size,
                              hipStream_t stream) {
    const float* x  = (const float*)d_in[0];   // 32*4096*256
    const float* Wu = (const float*)d_in[1];   // 256
    const float* Wh = (const float*)d_in[2];   // 512*512
    const float* H  = (const float*)d_in[3];   // 256*4096
    float* out = (float*)d_out;

    char* ws = (char*)d_ws;

    // new-path workspace layout (bytes)
    const size_t off_u   = 0;                                   // u: 131072 f32 (0.5 MB)
    const size_t off_xh  = off_u  + 524288;                     // xh: BT*256 fp16 (64 MB)
    const size_t off_whf = off_xh + 67108864;                   // whf: 512*512 fp16 (0.5 MB)
    const size_t off_U   = off_whf + 524288;                    // Uf: 32*8192 float2 (2 MB)
    const size_t off_Hf  = off_U  + 2097152;                    // Hf: 256*8192 float2 (16 MB)
    const size_t off_m2  = off_Hf + 16777216;                   // m2: 32*BT*8 fp16 (64 MB)
    const size_t need    = off_m2 + (size_t)MEM * BT * 2;       // ~147 MB

    if (ws_size >= need) {
        float*     ws_u   = (float*)(ws + off_u);
        _Float16*  ws_xh  = (_Float16*)(ws + off_xh);
        _Float16*  ws_whf = (_Float16*)(ws + off_whf);
        float2*    ws_U   = (float2*)(ws + off_U);
        float2*    ws_Hf  = (float2*)(ws + off_Hf);
        _Float16*  ws_m2  = (_Float16*)(ws + off_m2);

        wh_half_kernel<<<HID * HID / 4 / 256, 256, 0, stream>>>(Wh, ws_whf);
        relu_u_kernel<<<BT / 4, 256, 0, stream>>>(x, Wu, ws_u, ws_xh);
        fwd_all_kernel<<<BATCH + MEM, 512, 0, stream>>>(ws_u, H, ws_U, ws_Hf);
        conv_m_kernel<<<dim3(MEM / 8, BATCH), 512, 0, stream>>>(ws_U, ws_Hf, ws_m2);
        h_gemm_kernel<<<dim3(HID / 128, BT / 128), 256, 0, stream>>>(ws_xh, ws_whf, ws_m2, out);
    } else {
        // ---- old verified path (G-fold) ----
        float*  ws_u = (float*)ws;
        float2* ws_U = (float2*)(ws + 524288);
        float2* ws_G = (float2*)(ws + 524288 + 2097152);
        relu_u_kernel<<<BT / 4, 256, 0, stream>>>(x, Wu, ws_u, (_Float16*)(ws + 524288 + 2097152 + 33554432));
        fft_u_kernel<<<BATCH, 512, 0, stream>>>(ws_u, ws_U);
        g_fft_kernel<<<HID, 512, 0, stream>>>(Wh, H, ws_G);
        xw_gemm_kernel<<<dim3(HID / 128, BATCH * T / 128), 256, 0, stream>>>(x, Wh, out);
        conv_apply_kernel<<<dim3(HID / 2, BATCH), 512, 0, stream>>>(ws_U, ws_G, out);
    }
}

// Round 3
// 668.801 us; speedup vs baseline: 1.1073x; 1.1073x over previous
//
#include <hip/hip_runtime.h>
#include <hip/hip_bf16.h>
#include <math.h>

// LMU-FFT: x(32,4096,256), W_u(1,256), W_h(512,512), H(256,4096) -> h(32,4096,512), h_n(32,512)
//
// Round-3 structure (iFFT-then-GEMM, m97-style staged MFMA GEMM):
//   u = relu(x@W_u)            relu_u_kernel (also emits xh = fp16(x), row-major)
//   whfT = pack(W_h)           wh_pack_kernel: k-blocked fp16 [k/8][col][k%8]
//   Uf, Hf = FFT(u), FFT(H)    fwd_all_kernel (radix-4, digit-reversed order)
//   m = iFFT(Uf .* Hf-pairs)   conv_m_kernel: 4 iFFTs/block, packed fp16 into
//                              m2[q/8][b*T+t][q%8]  (16B-coalesced, k-blocked)
//   h = relu([m|x] @ W_h^T)    h_gemm_kernel: 128x128 tile, BK=64, 32KB LDS,
//                              global_load_lds(16B) staging (per-lane src, linear LDS),
//                              2-barrier K-loop, ds_read_b128 fragments, fp16 MFMA.
// All fp16 operands are k-blocked so staging chunks are contiguous 1KB wave loads
// and LDS fragment reads are contiguous 16B per lane (conflict-free).

#define BATCH 32
#define T     4096
#define IND   256
#define HID   512
#define MEM   256
#define FFT_N 8192
#define FFT_LOG 13
#define BT    131072   // BATCH*T

typedef __attribute__((ext_vector_type(8))) short short8;
typedef __attribute__((ext_vector_type(8))) _Float16 half8;
typedef __attribute__((ext_vector_type(4))) float f32x4;

__device__ inline short f2bf(float f) {
    unsigned u = __float_as_uint(f);
    unsigned r = (u + 0x7FFFu + ((u >> 16) & 1u)) >> 16;
    return (short)r;
}
__device__ inline unsigned pk2h(float a, float b) {
    union { _Float16 h[2]; unsigned u; } v;
    v.h[0] = (_Float16)a; v.h[1] = (_Float16)b;
    return v.u;
}
// async global->LDS, 16B per lane: LDS dest = wave-uniform base + lane*16,
// global src is per-lane. (m97/m173 pattern.)
__device__ __forceinline__ void gl_lds16(const void* g, void* l) {
    __builtin_amdgcn_global_load_lds((const __attribute__((address_space(1))) unsigned*)g,
                                     (__attribute__((address_space(3))) unsigned*)l, 16, 0, 0);
}

// ============================ kernel 1 ============================
// u[b,t] = relu(dot(x[b,t,:], W_u));  xh = fp16(x) row-major
__global__ __launch_bounds__(256) void relu_u_kernel(const float* __restrict__ x,
                                                     const float* __restrict__ Wu,
                                                     float* __restrict__ u,
                                                     _Float16* __restrict__ xh) {
    int wave = threadIdx.x >> 6, lane = threadIdx.x & 63;
    int r = blockIdx.x * 4 + wave;
    const float4 xv = *(const float4*)(x + (size_t)r * IND + lane * 4);
    const float4 wv = *(const float4*)(Wu + lane * 4);
    union { _Float16 h[4]; uint2 u2; } hv;
    hv.h[0] = (_Float16)xv.x; hv.h[1] = (_Float16)xv.y;
    hv.h[2] = (_Float16)xv.z; hv.h[3] = (_Float16)xv.w;
    *(uint2*)(xh + (size_t)r * IND + lane * 4) = hv.u2;
    float acc = xv.x * wv.x + xv.y * wv.y + xv.z * wv.z + xv.w * wv.w;
    for (int off = 32; off; off >>= 1) acc += __shfl_down(acc, off);
    if (lane == 0) u[r] = fmaxf(acc, 0.f);
}
// fallback variant without the xh side-write
__global__ __launch_bounds__(256) void relu_u_only_kernel(const float* __restrict__ x,
                                                          const float* __restrict__ Wu,
                                                          float* __restrict__ u) {
    int wave = threadIdx.x >> 6, lane = threadIdx.x & 63;
    int r = blockIdx.x * 4 + wave;
    const float4 xv = *(const float4*)(x + (size_t)r * IND + lane * 4);
    const float4 wv = *(const float4*)(Wu + lane * 4);
    float acc = xv.x * wv.x + xv.y * wv.y + xv.z * wv.z + xv.w * wv.w;
    for (int off = 32; off; off >>= 1) acc += __shfl_down(acc, off);
    if (lane == 0) u[r] = fmaxf(acc, 0.f);
}

// ============================ kernel 1b ============================
// whfT[k/8][col][k%8] = fp16(W_h[col][k])   (k-blocked, matches MFMA B-fragment)
__global__ __launch_bounds__(256) void wh_pack_kernel(const float* __restrict__ Wh,
                                                      _Float16* __restrict__ whfT) {
    int i = blockIdx.x * 256 + threadIdx.x;   // 65536 threads: (col, k-quad)
    int col = i >> 7;
    int kq  = (i & 127) << 2;                 // 0,4,...,508
    float4 v = *(const float4*)(Wh + (size_t)col * HID + kq);
    _Float16* d = whfT + (size_t)(kq >> 3) * (HID * 8) + (size_t)col * 8 + (kq & 7);
    d[0] = (_Float16)v.x; d[1] = (_Float16)v.y;
    d[2] = (_Float16)v.z; d[3] = (_Float16)v.w;
}

// ======================= radix-4 FFTs ==========================
// forward DIF: natural -> base-4-digit-reversed. Stages: R2(half=4096), R4 q=1024..1.
__device__ void fft_fwd_r4(float* re, float* im) {
    __syncthreads();
    {   // radix-2 stage, half = 4096
        const float fm = -(float)M_PI / 4096.f;
#pragma unroll
        for (int s = 0; s < 8; ++s) {
            int k = threadIdx.x + s * 512;
            float sn, cs; __sincosf(fm * (float)k, &sn, &cs);
            float ar = re[k], ai = im[k], br = re[k + 4096], bi = im[k + 4096];
            re[k] = ar + br; im[k] = ai + bi;
            float dr = ar - br, di = ai - bi;
            re[k + 4096] = cs * dr - sn * di;
            im[k + 4096] = cs * di + sn * dr;
        }
        __syncthreads();
    }
    for (int st = 10; st >= 0; st -= 2) {
        int q = 1 << st;
        float fm = -(float)M_PI / (float)(2 * q);
#pragma unroll
        for (int s = 0; s < 4; ++s) {
            int k = threadIdx.x + s * 512;
            int j = k & (q - 1);
            int i0 = ((k >> st) << (st + 2)) + j;
            float ar = re[i0],         ai = im[i0];
            float br = re[i0 + q],     bi = im[i0 + q];
            float cr = re[i0 + 2 * q], ci = im[i0 + 2 * q];
            float dr = re[i0 + 3 * q], di = im[i0 + 3 * q];
            float t0r = ar + cr, t0i = ai + ci;
            float t1r = ar - cr, t1i = ai - ci;
            float t2r = br + dr, t2i = bi + di;
            float t3r = bi - di, t3i = dr - br;      // -i*(b-d)
            float sn, cs; __sincosf(fm * (float)j, &sn, &cs);   // w = cs + i*sn
            float w2r = cs * cs - sn * sn, w2i = 2.f * cs * sn; // w^2
            float w3r = w2r * cs - w2i * sn, w3i = w2r * sn + w2i * cs; // w^3
            re[i0] = t0r + t2r;               im[i0] = t0i + t2i;
            float er = t0r - t2r, ei = t0i - t2i;
            re[i0 + q] = er * w2r - ei * w2i; im[i0 + q] = er * w2i + ei * w2r;
            float fr = t1r + t3r, fi = t1i + t3i;
            re[i0 + 2 * q] = fr * cs - fi * sn; im[i0 + 2 * q] = fr * sn + fi * cs;
            float gr = t1r - t3r, gi = t1i - t3i;
            re[i0 + 3 * q] = gr * w3r - gi * w3i; im[i0 + 3 * q] = gr * w3i + gi * w3r;
        }
        __syncthreads();
    }
}
// inverse (unscaled): digit-reversed -> natural. Exact transpose of fwd.
__device__ void fft_inv_r4(float* re, float* im) {
    __syncthreads();
    for (int st = 0; st <= 10; st += 2) {
        int q = 1 << st;
        float fm = (float)M_PI / (float)(2 * q);       // conj twiddles
#pragma unroll
        for (int s = 0; s < 4; ++s) {
            int k = threadIdx.x + s * 512;
            int j = k & (q - 1);
            int i0 = ((k >> st) << (st + 2)) + j;
            float Ar = re[i0],         Ai = im[i0];
            float Br = re[i0 + q],     Bi = im[i0 + q];
            float Cr = re[i0 + 2 * q], Ci = im[i0 + 2 * q];
            float Dr = re[i0 + 3 * q], Di = im[i0 + 3 * q];
            float sn, cs; __sincosf(fm * (float)j, &sn, &cs);   // wbar = cs + i*sn
            float w2r = cs * cs - sn * sn, w2i = 2.f * cs * sn;
            float w3r = w2r * cs - w2i * sn, w3i = w2r * sn + w2i * cs;
            float bpr = Br * w2r - Bi * w2i, bpi = Br * w2i + Bi * w2r;
            float cpr = Cr * cs - Ci * sn,   cpi = Cr * sn + Ci * cs;
            float dpr = Dr * w3r - Di * w3i, dpi = Dr * w3i + Di * w3r;
            float t0r = Ar + bpr, t0i = Ai + bpi;
            float t2r = Ar - bpr, t2i = Ai - bpi;
            float t1r = cpr + dpr, t1i = cpi + dpi;
            float t3r = cpr - dpr, t3i = cpi - dpi;
            re[i0]         = t0r + t1r; im[i0]         = t0i + t1i;
            re[i0 + 2 * q] = t0r - t1r; im[i0 + 2 * q] = t0i - t1i;
            re[i0 + q]     = t2r - t3i; im[i0 + q]     = t2i + t3r;  // t2' + i*t3'
            re[i0 + 3 * q] = t2r + t3i; im[i0 + 3 * q] = t2i - t3r;  // t2' - i*t3'
        }
        __syncthreads();
    }
    {   // radix-2 stage, half = 4096, conj twiddle
        const float fm = (float)M_PI / 4096.f;
#pragma unroll
        for (int s = 0; s < 8; ++s) {
            int k = threadIdx.x + s * 512;
            float sn, cs; __sincosf(fm * (float)k, &sn, &cs);
            float br = re[k + 4096], bi = im[k + 4096];
            float tr = cs * br - sn * bi, ti = cs * bi + sn * br;
            float ar = re[k], ai = im[k];
            re[k] = ar + tr;        im[k] = ai + ti;
            re[k + 4096] = ar - tr; im[k + 4096] = ai - ti;
        }
        __syncthreads();
    }
}

// ============================ kernel 2 ============================
// forward FFTs of u rows (blocks 0..31) and H rows (blocks 32..287)
__global__ __launch_bounds__(512) void fwd_all_kernel(const float* __restrict__ u,
                                                      const float* __restrict__ H,
                                                      float2* __restrict__ Uf,
                                                      float2* __restrict__ Hf) {
    __shared__ float re[FFT_N];
    __shared__ float im[FFT_N];
    int r = blockIdx.x;
    const float* src = (r < BATCH) ? (u + (size_t)r * T) : (H + (size_t)(r - BATCH) * T);
    float2* dst = (r < BATCH) ? (Uf + (size_t)r * FFT_N) : (Hf + (size_t)(r - BATCH) * FFT_N);
    for (int i = threadIdx.x; i < FFT_N; i += 512) {
        re[i] = (i < T) ? src[i] : 0.f;
        im[i] = 0.f;
    }
    fft_fwd_r4(re, im);
    for (int i = threadIdx.x; i < FFT_N; i += 512) dst[i] = make_float2(re[i], im[i]);
}

// ============================ kernel 3 ============================
// per (qblock, b): 4 iFFTs (8 q-channels), pack fp16, write m2[qb][b*T+t][0..7]
__global__ __launch_bounds__(512) void conv_m_kernel(const float2* __restrict__ Uf,
                                                     const float2* __restrict__ Hf,
                                                     _Float16* __restrict__ m2) {
    int qb = blockIdx.x;   // 0..31
    int b  = blockIdx.y;   // 0..31
    __shared__ float re[FFT_N];
    __shared__ float im[FFT_N];
    const float2* Ub = Uf + (size_t)b * FFT_N;
    const float inv = 1.0f / (float)FFT_N;
    unsigned p0[8], p1[8], p2[8], p3[8];

#define DO_FF(FF, PK)                                                          \
    {                                                                          \
        const float2* Ha = Hf + (size_t)(qb * 8 + 2 * (FF)) * FFT_N;           \
        const float2* Hb = Ha + FFT_N;                                         \
        for (int f = threadIdx.x; f < FFT_N; f += 512) {                       \
            float2 uv = Ub[f], h0 = Ha[f], h1 = Hb[f];                         \
            float gr = h0.x - h1.y, gi = h0.y + h1.x;  /* h0 + i*h1 */         \
            re[f] = uv.x * gr - uv.y * gi;                                     \
            im[f] = uv.x * gi + uv.y * gr;                                     \
        }                                                                      \
        fft_inv_r4(re, im);                                                    \
        _Pragma("unroll")                                                      \
        for (int it = 0; it < 8; ++it) {                                       \
            int tt = threadIdx.x + it * 512;                                   \
            PK[it] = pk2h(re[tt] * inv, im[tt] * inv);                         \
        }                                                                      \
    }

    DO_FF(0, p0)
    DO_FF(1, p1)
    DO_FF(2, p2)
    DO_FF(3, p3)
#undef DO_FF

    _Float16* dst = m2 + ((size_t)qb * BT + (size_t)b * T) * 8;
#pragma unroll
    for (int it = 0; it < 8; ++it) {
        int tt = threadIdx.x + it * 512;
        uint4 w;
        w.x = p0[it]; w.y = p1[it]; w.z = p2[it]; w.w = p3[it];
        *(uint4*)(dst + (size_t)tt * 8) = w;   // 16B, fully coalesced over t
    }
}

// ============================ kernel 4 ============================
// h = relu([m | x] @ W_h^T), fp16 MFMA, K=512. 128x128 tile, BK=64, 4 waves.
// m97 structure: global_load_lds(16B) staging into 32KB linear LDS, 2 barriers
// per K-step, ds_read_b128 fragments, fully unrolled 8-step K-loop.
__global__ __launch_bounds__(256) void h_gemm_kernel(const _Float16* __restrict__ xh,
                                                     const _Float16* __restrict__ whfT,
                                                     const _Float16* __restrict__ m2,
                                                     float* __restrict__ out) {
    __shared__ __align__(16) _Float16 As[8][128][8];   // 16KB  [k-octet][row][elem]
    __shared__ __align__(16) _Float16 Bs[8][128][8];   // 16KB  [k-octet][col][elem]
    int bn = blockIdx.x;     // 0..3
    int bm = blockIdx.y;     // 0..1023
    int t = threadIdx.x;
    int wv = t >> 6, lane = t & 63;
    int wm = (wv & 1) * 64, wn = (wv >> 1) * 64;
    int ln = lane & 15, kg = lane >> 4;

    f32x4 acc[4][4] = {};
#pragma unroll
    for (int ks = 0; ks < 8; ++ks) {
        int kc = ks * 64;
        __syncthreads();   // previous step's fragment reads complete
        // stage BK=64 tile: 32 x 1KB chunks (16 A + 16 B), 8 per wave
#pragma unroll
        for (int q = 0; q < 8; ++q) {
            int c = wv * 8 + q;
            int g = (c & 15) >> 1;     // k-octet within tile (0..7)
            int rg = c & 1;            // row-group (0..1)
            int row = rg * 64 + lane;
            if (c < 16) {
                const void* src;
                if (kc < MEM)
                    src = m2 + ((size_t)(kc / 8 + g) * BT + (size_t)bm * 128 + row) * 8;
                else
                    src = xh + (size_t)(bm * 128 + row) * IND + (kc - MEM) + g * 8;
                gl_lds16(src, &As[g][rg * 64][0]);
            } else {
                const void* src = whfT + (size_t)(kc / 8 + g) * (HID * 8)
                                       + (size_t)(bn * 128 + row) * 8;
                gl_lds16(src, &Bs[g][rg * 64][0]);
            }
        }
        __syncthreads();   // drains vmcnt(0): staged tile visible
        half8 af[2][4], bf[2][4];
#pragma unroll
        for (int kk = 0; kk < 2; ++kk) {
#pragma unroll
            for (int i = 0; i < 4; ++i)
                af[kk][i] = *(const half8*)&As[kk * 4 + kg][wm + i * 16 + ln][0];
#pragma unroll
            for (int j = 0; j < 4; ++j)
                bf[kk][j] = *(const half8*)&Bs[kk * 4 + kg][wn + j * 16 + ln][0];
        }
#pragma unroll
        for (int kk = 0; kk < 2; ++kk)
#pragma unroll
            for (int i = 0; i < 4; ++i)
#pragma unroll
                for (int j = 0; j < 4; ++j)
                    acc[i][j] = __builtin_amdgcn_mfma_f32_16x16x32_f16(af[kk][i], bf[kk][j],
                                                                       acc[i][j], 0, 0, 0);
    }
#pragma unroll
    for (int i = 0; i < 4; ++i) {
#pragma unroll
        for (int j = 0; j < 4; ++j) {
#pragma unroll
            for (int r = 0; r < 4; ++r) {
                int row = bm * 128 + wm + i * 16 + kg * 4 + r;
                int col = bn * 128 + wn + j * 16 + ln;
                float v = fmaxf(acc[i][j][r], 0.f);
                out[(size_t)row * HID + col] = v;
                if ((row & (T - 1)) == (T - 1))
                    out[(size_t)BATCH * T * HID + (size_t)(row >> 12) * HID + col] = v;
            }
        }
    }
}

// ================== OLD PATH (verbatim fallback, small ws) ==================
__device__ void fft_dif_fwd(float* re, float* im) {
    __syncthreads();
    for (int st = FFT_LOG; st >= 1; --st) {
        int half = 1 << (st - 1);
        float fm = -(float)M_PI / (float)half;
        for (int k = threadIdx.x; k < FFT_N / 2; k += 512) {
            int j  = k & (half - 1);
            int i1 = ((k >> (st - 1)) << st) + j;
            int i2 = i1 + half;
            float sn, cs;
            __sincosf(fm * (float)j, &sn, &cs);
            float ar = re[i1], ai = im[i1];
            float br = re[i2], bi = im[i2];
            re[i1] = ar + br; im[i1] = ai + bi;
            float dr = ar - br, di = ai - bi;
            re[i2] = cs * dr - sn * di;
            im[i2] = cs * di + sn * dr;
        }
        __syncthreads();
    }
}
__device__ void fft_dit_inv(float* re, float* im) {
    __syncthreads();
    for (int st = 1; st <= FFT_LOG; ++st) {
        int half = 1 << (st - 1);
        float fm = (float)M_PI / (float)half;
        for (int k = threadIdx.x; k < FFT_N / 2; k += 512) {
            int j  = k & (half - 1);
            int i1 = ((k >> (st - 1)) << st) + j;
            int i2 = i1 + half;
            float sn, cs;
            __sincosf(fm * (float)j, &sn, &cs);
            float br = re[i2], bi = im[i2];
            float tr = cs * br - sn * bi;
            float ti = cs * bi + sn * br;
            float ar = re[i1], ai = im[i1];
            re[i1] = ar + tr; im[i1] = ai + ti;
            re[i2] = ar - tr; im[i2] = ai - ti;
        }
        __syncthreads();
    }
}
__global__ __launch_bounds__(512) void fft_u_kernel(const float* __restrict__ u,
                                                    float2* __restrict__ Uf) {
    int b = blockIdx.x;
    __shared__ float re[FFT_N];
    __shared__ float im[FFT_N];
    for (int i = threadIdx.x; i < FFT_N; i += 512) {
        re[i] = i < T ? u[(size_t)b * T + i] : 0.f;
        im[i] = 0.f;
    }
    fft_dif_fwd(re, im);
    for (int i = threadIdx.x; i < FFT_N; i += 512)
        Uf[(size_t)b * FFT_N + i] = make_float2(re[i], im[i]);
}
__global__ __launch_bounds__(512) void g_fft_kernel(const float* __restrict__ Wh,
                                                    const float* __restrict__ H,
                                                    float2* __restrict__ Gf) {
    int o = blockIdx.x;
    __shared__ float re[FFT_N];
    __shared__ float im[FFT_N];
    const float* wrow = Wh + (size_t)o * HID;
    float acc[8];
#pragma unroll
    for (int d = 0; d < 8; ++d) acc[d] = 0.f;
    for (int q = 0; q < 256; ++q) {
        float w = wrow[q];
        const float* hrow = H + (size_t)q * T;
#pragma unroll
        for (int d = 0; d < 8; ++d)
            acc[d] = fmaf(w, hrow[threadIdx.x + d * 512], acc[d]);
    }
#pragma unroll
    for (int d = 0; d < 8; ++d) {
        re[threadIdx.x + d * 512] = acc[d];
        im[threadIdx.x + d * 512] = 0.f;
    }
    for (int i = T + threadIdx.x; i < FFT_N; i += 512) { re[i] = 0.f; im[i] = 0.f; }
    fft_dif_fwd(re, im);
    for (int i = threadIdx.x; i < FFT_N; i += 512)
        Gf[(size_t)o * FFT_N + i] = make_float2(re[i], im[i]);
}
__global__ __launch_bounds__(256) void xw_gemm_kernel(const float* __restrict__ x,
                                                      const float* __restrict__ Wh,
                                                      float* __restrict__ out) {
    __shared__ __align__(16) short Asl[4][128][8];
    __shared__ __align__(16) short Bsl[4][128][8];
    int bn = blockIdx.x;
    int bm = blockIdx.y;
    int t = threadIdx.x;
    int wv = t >> 6, lane = t & 63;
    int wm = (wv & 1) * 64, wn = (wv >> 1) * 64;
    int ln = lane & 15, kg = lane >> 4;
    f32x4 acc[4][4] = {};
    int mrow = t >> 1, khalf = t & 1;
    for (int kc = 0; kc < IND; kc += 32) {
        {
            const float* xr = x + ((size_t)(bm * 128 + mrow)) * IND + kc + khalf * 16;
            float4 v0 = *(const float4*)(xr + 0);
            float4 v1 = *(const float4*)(xr + 4);
            float4 v2 = *(const float4*)(xr + 8);
            float4 v3 = *(const float4*)(xr + 12);
            short8 s0 = { f2bf(v0.x), f2bf(v0.y), f2bf(v0.z), f2bf(v0.w),
                          f2bf(v1.x), f2bf(v1.y), f2bf(v1.z), f2bf(v1.w) };
            short8 s1 = { f2bf(v2.x), f2bf(v2.y), f2bf(v2.z), f2bf(v2.w),
                          f2bf(v3.x), f2bf(v3.y), f2bf(v3.z), f2bf(v3.w) };
            const float* wr = Wh + ((size_t)(bn * 128 + mrow)) * HID + 256 + kc + khalf * 16;
            float4 w0 = *(const float4*)(wr + 0);
            float4 w1 = *(const float4*)(wr + 4);
            float4 w2 = *(const float4*)(wr + 8);
            float4 w3 = *(const float4*)(wr + 12);
            short8 b0 = { f2bf(w0.x), f2bf(w0.y), f2bf(w0.z), f2bf(w0.w),
                          f2bf(w1.x), f2bf(w1.y), f2bf(w1.z), f2bf(w1.w) };
            short8 b1 = { f2bf(w2.x), f2bf(w2.y), f2bf(w2.z), f2bf(w2.w),
                          f2bf(w3.x), f2bf(w3.y), f2bf(w3.z), f2bf(w3.w) };
            __syncthreads();
            *(short8*)&Asl[khalf * 2 + 0][mrow][0] = s0;
            *(short8*)&Asl[khalf * 2 + 1][mrow][0] = s1;
            *(short8*)&Bsl[khalf * 2 + 0][mrow][0] = b0;
            *(short8*)&Bsl[khalf * 2 + 1][mrow][0] = b1;
            __syncthreads();
        }
        short8 af[4], bf[4];
#pragma unroll
        for (int i = 0; i < 4; ++i) af[i] = *(short8*)&Asl[kg][wm + i * 16 + ln][0];
#pragma unroll
        for (int j = 0; j < 4; ++j) bf[j] = *(short8*)&Bsl[kg][wn + j * 16 + ln][0];
#pragma unroll
        for (int i = 0; i < 4; ++i)
#pragma unroll
            for (int j = 0; j < 4; ++j)
                acc[i][j] = __builtin_amdgcn_mfma_f32_16x16x32_bf16(af[i], bf[j], acc[i][j], 0, 0, 0);
    }
#pragma unroll
    for (int i = 0; i < 4; ++i) {
#pragma unroll
        for (int j = 0; j < 4; ++j) {
#pragma unroll
            for (int r = 0; r < 4; ++r) {
                int row = bm * 128 + wm + i * 16 + (lane >> 4) * 4 + r;
                int col = bn * 128 + wn + j * 16 + (lane & 15);
                out[(size_t)row * HID + col] = acc[i][j][r];
            }
        }
    }
}
__global__ __launch_bounds__(512) void conv_apply_kernel(const float2* __restrict__ Uf,
                                                         const float2* __restrict__ Gf,
                                                         float* __restrict__ out) {
    int p = blockIdx.x;
    int b = blockIdx.y;
    __shared__ float re[FFT_N];
    __shared__ float im[FFT_N];
    const float2* Ub = Uf + (size_t)b * FFT_N;
    const float2* G0 = Gf + (size_t)(2 * p) * FFT_N;
    const float2* G1 = Gf + (size_t)(2 * p + 1) * FFT_N;
    for (int f = threadIdx.x; f < FFT_N; f += 512) {
        float2 uv = Ub[f], g0 = G0[f], g1 = G1[f];
        float gr = g0.x - g1.y, gi = g0.y + g1.x;
        re[f] = uv.x * gr - uv.y * gi;
        im[f] = uv.x * gi + uv.y * gr;
    }
    fft_dit_inv(re, im);
    const float inv = 1.0f / (float)FFT_N;
    for (int t = threadIdx.x; t < T; t += 512) {
        size_t idx = ((size_t)(b * T + t)) * HID + 2 * p;
        float2 xw = *(const float2*)(out + idx);
        float v0 = fmaxf(fmaf(re[t], inv, xw.x), 0.f);
        float v1 = fmaxf(fmaf(im[t], inv, xw.y), 0.f);
        *(float2*)(out + idx) = make_float2(v0, v1);
        if (t == T - 1) {
            size_t hn = (size_t)BATCH * T * HID + (size_t)b * HID + 2 * p;
            *(float2*)(out + hn) = make_float2(v0, v1);
        }
    }
}

// ============================== launch ==============================
extern "C" void kernel_launch(void* const* d_in, const int* in_sizes, int n_in,
                              void* d_out, int out_size, void* d_ws, size_t ws_size,
                              hipStream_t stream) {
    const float* x  = (const float*)d_in[0];   // 32*4096*256
    const float* Wu = (const float*)d_in[1];   // 256
    const float* Wh = (const float*)d_in[2];   // 512*512
    const float* H  = (const float*)d_in[3];   // 256*4096
    float* out = (float*)d_out;

    char* ws = (char*)d_ws;

    // new-path workspace layout (bytes)
    const size_t off_u   = 0;                                   // u: 131072 f32 (0.5 MB)
    const size_t off_xh  = off_u  + 524288;                     // xh: BT*256 fp16 (64 MB)
    const size_t off_whf = off_xh + 67108864;                   // whfT: 512*512 fp16 (0.5 MB)
    const size_t off_U   = off_whf + 524288;                    // Uf: 32*8192 float2 (2 MB)
    const size_t off_Hf  = off_U  + 2097152;                    // Hf: 256*8192 float2 (16 MB)
    const size_t off_m2  = off_Hf + 16777216;                   // m2: 32*BT*8 fp16 (64 MB)
    const size_t need    = off_m2 + (size_t)MEM * BT * 2;       // ~147 MB

    if (ws_size >= need) {
        float*     ws_u    = (float*)(ws + off_u);
        _Float16*  ws_xh   = (_Float16*)(ws + off_xh);
        _Float16*  ws_whfT = (_Float16*)(ws + off_whf);
        float2*    ws_U    = (float2*)(ws + off_U);
        float2*    ws_Hf   = (float2*)(ws + off_Hf);
        _Float16*  ws_m2   = (_Float16*)(ws + off_m2);

        wh_pack_kernel<<<HID * HID / 4 / 256, 256, 0, stream>>>(Wh, ws_whfT);
        relu_u_kernel<<<BT / 4, 256, 0, stream>>>(x, Wu, ws_u, ws_xh);
        fwd_all_kernel<<<BATCH + MEM, 512, 0, stream>>>(ws_u, H, ws_U, ws_Hf);
        conv_m_kernel<<<dim3(MEM / 8, BATCH), 512, 0, stream>>>(ws_U, ws_Hf, ws_m2);
        h_gemm_kernel<<<dim3(HID / 128, BT / 128), 256, 0, stream>>>(ws_xh, ws_whfT, ws_m2, out);
    } else {
        // ---- old verified path (G-fold) ----
        float*  ws_u = (float*)ws;
        float2* ws_U = (float2*)(ws + 524288);
        float2* ws_G = (float2*)(ws + 524288 + 2097152);
        relu_u_only_kernel<<<BT / 4, 256, 0, stream>>>(x, Wu, ws_u);
        fft_u_kernel<<<BATCH, 512, 0, stream>>>(ws_u, ws_U);
        g_fft_kernel<<<HID, 512, 0, stream>>>(Wh, H, ws_G);
        xw_gemm_kernel<<<dim3(HID / 128, BATCH * T / 128), 256, 0, stream>>>(x, Wh, out);
        conv_apply_kernel<<<dim3(HID / 2, BATCH), 512, 0, stream>>>(ws_U, ws_G, out);
    }
}